// Round 8
// baseline (478.696 us; speedup 1.0000x reference)
//
#include <hip/hip_runtime.h>
#include <cstdint>
#include <cstddef>

typedef _Float16 half8 __attribute__((ext_vector_type(8)));
typedef _Float16 half4 __attribute__((ext_vector_type(4)));
typedef float f32x4 __attribute__((ext_vector_type(4)));

#define GAT_N 8192
#define GAT_F 256
#define GAT_NW 256   // adj bitmask words per row (8192/32)
#define GAT_ALPHA 0.2f
#define GAT_LOG2E 1.4426950408889634f

// Monotone float->uint encoding for atomicMax over floats of any sign.
__device__ inline unsigned enc_f32(float x) {
    unsigned b = __float_as_uint(x);
    return (b & 0x80000000u) ? ~b : (b | 0x80000000u);
}
__device__ inline float dec_f32(unsigned u) {
    unsigned b = (u & 0x80000000u) ? (u ^ 0x80000000u) : ~u;
    return __uint_as_float(b);
}

// ---------------------------------------------------------------------------
// K0a: bit-pack adj (int32 0/1, 268 MB) -> adjB (1 bit/edge, 8 MB).
// ---------------------------------------------------------------------------
__global__ __launch_bounds__(256) void gat_k0_pack(
    const int* __restrict__ adj, unsigned char* __restrict__ adjB)
{
    const int wv = threadIdx.x >> 6;
    const int lane = threadIdx.x & 63;
    const int row = blockIdx.x * 4 + wv;
    const int* src = adj + (size_t)row * GAT_N;
    unsigned char* dst = adjB + (size_t)row * (GAT_N / 8);
    #pragma unroll 4
    for (int k = 0; k < 16; ++k) {
        const int4 v0 = *reinterpret_cast<const int4*>(src + k * 512 + lane * 8);
        const int4 v1 = *reinterpret_cast<const int4*>(src + k * 512 + lane * 8 + 4);
        unsigned m = (unsigned)(v0.x > 0)        | ((unsigned)(v0.y > 0) << 1)
                   | ((unsigned)(v0.z > 0) << 2) | ((unsigned)(v0.w > 0) << 3)
                   | ((unsigned)(v1.x > 0) << 4) | ((unsigned)(v1.y > 0) << 5)
                   | ((unsigned)(v1.z > 0) << 6) | ((unsigned)(v1.w > 0) << 7);
        dst[k * 64 + lane] = (unsigned char)m;
    }
}

// ---------------------------------------------------------------------------
// K0b: W -> fp16 transposed WT[n][k]; init encoded f2max.
// ---------------------------------------------------------------------------
__global__ __launch_bounds__(256) void gat_k0b_convert(
    const float* __restrict__ W, _Float16* __restrict__ WT,
    unsigned* __restrict__ f2mxEnc)
{
    const int g = blockIdx.x * 256 + threadIdx.x;
    if (g == 0) *f2mxEnc = 0u;                          // enc(-FLT_MAX)
    const int k = g >> 8, n = g & 255;
    WT[n * GAT_F + k] = (_Float16)W[g];
}

// ---------------------------------------------------------------------------
// K1: Wh = h @ W via fp16 MFMA. grid 512 x 256 thr: block = 16 rows,
// wave wv = col-quarter (64 cols, 4 tiles). Cross-wave f1/f2 via LDS.
// ---------------------------------------------------------------------------
__global__ __launch_bounds__(256, 2) void gat_k1_gemm(
    const float* __restrict__ h, const _Float16* __restrict__ WT,
    const float* __restrict__ a, _Float16* __restrict__ whT,
    float* __restrict__ f1L, float* __restrict__ f2L,
    unsigned* __restrict__ f2mxEnc)
{
    __shared__ float sP1[4][16], sP2[4][16];
    const int wv = threadIdx.x >> 6;
    const int lane = threadIdx.x & 63;
    const int l15 = lane & 15;
    const int quad = lane >> 4;
    const int r0 = blockIdx.x * 16;

    f32x4 acc[4];
    #pragma unroll
    for (int t = 0; t < 4; ++t) { f32x4 z = {0.f,0.f,0.f,0.f}; acc[t] = z; }

    #pragma unroll
    for (int k0 = 0; k0 < GAT_F; k0 += 32) {
        const float* ap = h + (size_t)(r0 + l15) * GAT_F + k0 + quad * 8;
        const float4 a0 = *reinterpret_cast<const float4*>(ap);
        const float4 a1 = *reinterpret_cast<const float4*>(ap + 4);
        half8 af;
        af[0] = (_Float16)a0.x; af[1] = (_Float16)a0.y;
        af[2] = (_Float16)a0.z; af[3] = (_Float16)a0.w;
        af[4] = (_Float16)a1.x; af[5] = (_Float16)a1.y;
        af[6] = (_Float16)a1.z; af[7] = (_Float16)a1.w;
        #pragma unroll
        for (int t = 0; t < 4; ++t) {
            half8 bf = *reinterpret_cast<const half8*>(
                WT + (size_t)(wv * 64 + t * 16 + l15) * GAT_F + k0 + quad * 8);
            acc[t] = __builtin_amdgcn_mfma_f32_16x16x32_f16(af, bf, acc[t], 0, 0, 0);
        }
    }

    float p1[4] = {0.f,0.f,0.f,0.f}, p2[4] = {0.f,0.f,0.f,0.f};
    #pragma unroll
    for (int t = 0; t < 4; ++t) {
        float a1c = a[wv * 64 + t * 16 + l15];
        float a2c = a[GAT_F + wv * 64 + t * 16 + l15];
        #pragma unroll
        for (int r = 0; r < 4; ++r) {
            p1[r] = fmaf(acc[t][r], a1c, p1[r]);
            p2[r] = fmaf(acc[t][r], a2c, p2[r]);
        }
    }
    #pragma unroll
    for (int off = 1; off < 16; off <<= 1) {
        #pragma unroll
        for (int r = 0; r < 4; ++r) {
            p1[r] += __shfl_xor(p1[r], off);
            p2[r] += __shfl_xor(p2[r], off);
        }
    }
    if (l15 == 0) {
        #pragma unroll
        for (int r = 0; r < 4; ++r) {
            sP1[wv][quad * 4 + r] = p1[r];
            sP2[wv][quad * 4 + r] = p2[r];
        }
    }
    __syncthreads();
    if (threadIdx.x < 16) {
        const int row = threadIdx.x;
        const float s1 = (sP1[0][row] + sP1[1][row] + sP1[2][row] + sP1[3][row]) * GAT_LOG2E;
        const float s2 = (sP2[0][row] + sP2[1][row] + sP2[2][row] + sP2[3][row]) * GAT_LOG2E;
        f1L[r0 + row] = s1;
        f2L[r0 + row] = s2;
        float mx = s2;
        #pragma unroll
        for (int off = 1; off < 16; off <<= 1) mx = fmaxf(mx, __shfl_xor(mx, off));
        if (row == 0) atomicMax(f2mxEnc, enc_f32(mx));
    }

    #pragma unroll
    for (int t = 0; t < 4; ++t) {
        half4 hv;
        #pragma unroll
        for (int r = 0; r < 4; ++r) hv[r] = (_Float16)acc[t][r];
        *reinterpret_cast<half4*>(
            whT + (size_t)(wv * 64 + t * 16 + l15) * GAT_N + r0 + quad * 4) = hv;
    }
}

// ---------------------------------------------------------------------------
// K2e: per-key softmax tables. E[j]=2^(f2j-fmx), E5[j]=2^(0.2(f2j-fmx)).
// Makes K3 exp-free: p_ij = adj * (x>=0 ? E_j*K_i : E5_j*M_i), sign test via
// E_j >= T_i (exp2 monotone).
// ---------------------------------------------------------------------------
__global__ __launch_bounds__(256) void gat_k2e_tables(
    const float* __restrict__ f2L, const unsigned* __restrict__ f2mxEnc,
    float* __restrict__ E, float* __restrict__ E5)
{
    const int i = blockIdx.x * 256 + threadIdx.x;      // 8192
    const float d = f2L[i] - dec_f32(*f2mxEnc);
    E[i]  = __builtin_amdgcn_exp2f(d);
    E5[i] = __builtin_amdgcn_exp2f(GAT_ALPHA * d);
}

// ---------------------------------------------------------------------------
// K3: fused masked softmax-numerator x V, fp16 MFMA, bitmask adjacency,
// EXP-FREE inner loop via E/E5 tables.
// grid = 32 rb x 8 q x 2 fh = 512 blocks = EXACTLY 2 blocks/CU, no tail.
// Block: 256 rows x 128 feats x 1024-key slice. Wave: 64 rows (4 strips of
// 16), so each LDS B-fragment feeds 4 MFMAs (halves LDS-pipe load/FLOP).
// acc = 4x8x4 = 128 VGPR; working set ~220 < 256 -> 2 waves/SIMD, no spill.
// BK=64 double-buffered LDS (2 x 16 KB), key-oct-major conflict-free layout.
// ---------------------------------------------------------------------------
__global__ __launch_bounds__(256, 2) void gat_k3_attn(
    const unsigned* __restrict__ adjW, const float* __restrict__ f1L,
    const unsigned* __restrict__ f2mxEnc,
    const float* __restrict__ E, const float* __restrict__ E5,
    const _Float16* __restrict__ whT,
    _Float16* __restrict__ Ph,     // [q][wid][fh] permuted fp16 partials
    float* __restrict__ L)         // [8][8192]
{
    __shared__ __align__(16) _Float16 sB[2][8192];   // 2 x 16 KB (64-key tile)

    const int bx = blockIdx.x;
    const int q  = bx & 7;           // key slice (bx%8 ~ XCD spread)
    const int fh = (bx >> 3) & 1;    // feature half
    const int rb = bx >> 4;          // row group 0..31 (256 rows)
    const int wv = threadIdx.x >> 6;
    const int lane = threadIdx.x & 63;
    const int l15 = lane & 15;
    const int quad = lane >> 4;

    const int r0 = rb * 256 + wv * 64;   // wave's 64 rows

    const float fmxL = dec_f32(*f2mxEnc);
    // Per-strip row constants: T (sign threshold), K (pos factor), M (neg).
    float Tc[4], Kc[4], Mc[4];
    #pragma unroll
    for (int s = 0; s < 4; ++s) {
        const float sA = f1L[r0 + s * 16 + l15] + fmxL;
        const float C = fmaxf(sA, GAT_ALPHA * sA);
        Tc[s] = __builtin_amdgcn_exp2f(-sA);
        Kc[s] = __builtin_amdgcn_exp2f(sA - C);
        Mc[s] = __builtin_amdgcn_exp2f(GAT_ALPHA * sA - C);
    }

    f32x4 acc[4][8];
    #pragma unroll
    for (int s = 0; s < 4; ++s)
        #pragma unroll
        for (int t = 0; t < 8; ++t) {
            f32x4 z = {0.f,0.f,0.f,0.f};
            acc[s][t] = z;
        }
    float dsum[4] = {0.f, 0.f, 0.f, 0.f};

    const int kq = q * 1024;
    const uint2* aw0 = reinterpret_cast<const uint2*>(adjW + (size_t)(r0 + 0*16 + l15) * GAT_NW + q * 32);
    const uint2* aw1 = reinterpret_cast<const uint2*>(adjW + (size_t)(r0 + 1*16 + l15) * GAT_NW + q * 32);
    const uint2* aw2 = reinterpret_cast<const uint2*>(adjW + (size_t)(r0 + 2*16 + l15) * GAT_NW + q * 32);
    const uint2* aw3 = reinterpret_cast<const uint2*>(adjW + (size_t)(r0 + 3*16 + l15) * GAT_NW + q * 32);
    const float* Eq  = E  + kq + quad * 8;
    const float* E5q = E5 + kq + quad * 8;

    // Staging: 128 feats x 64 keys (16 KB), 4 instr/wave, key-oct-major.
    const _Float16* gst = whT + (size_t)(fh * 128 + lane) * GAT_N + kq + wv * 8;
    #define STAGE(buf, step)                                                   \
        {                                                                      \
            _Pragma("unroll")                                                  \
            for (int i = 0; i < 4; ++i) {                                      \
                const _Float16* gp = gst + (size_t)((i & 1) * 64) * GAT_N      \
                                     + (i >> 1) * 32 + (step) * 64;            \
                _Float16* lp = &sB[buf][((wv + (i >> 1) * 4) * 128             \
                                         + (i & 1) * 64) * 8];                 \
                __builtin_amdgcn_global_load_lds(                              \
                    (const __attribute__((address_space(1))) void*)gp,         \
                    (__attribute__((address_space(3))) void*)lp, 16, 0, 0);    \
            }                                                                  \
        }

    uint2 n0 = aw0[0], n1 = aw1[0], n2 = aw2[0], n3 = aw3[0];
    float4 nEa = *reinterpret_cast<const float4*>(Eq);
    float4 nEb = *reinterpret_cast<const float4*>(Eq + 4);
    float4 nFa = *reinterpret_cast<const float4*>(E5q);
    float4 nFb = *reinterpret_cast<const float4*>(E5q + 4);
    STAGE(0, 0)
    __syncthreads();

    for (int step = 0; step < 16; ++step) {   // 64 keys per step
        const int cur = step & 1;
        const uint2 c0 = n0, c1 = n1, c2 = n2, c3 = n3;
        if (step < 15) {
            n0 = aw0[step + 1]; n1 = aw1[step + 1];
            n2 = aw2[step + 1]; n3 = aw3[step + 1];
            STAGE(1 - cur, step + 1)
        }

        #pragma unroll
        for (int k2 = 0; k2 < 2; ++k2) {    // 32 keys (one MFMA K)
            const int u = step * 2 + k2;
            const float4 cEa = nEa, cEb = nEb, cFa = nFa, cFb = nFb;
            if (u < 31) {
                nEa = *reinterpret_cast<const float4*>(Eq + (u + 1) * 32);
                nEb = *reinterpret_cast<const float4*>(Eq + (u + 1) * 32 + 4);
                nFa = *reinterpret_cast<const float4*>(E5q + (u + 1) * 32);
                nFb = *reinterpret_cast<const float4*>(E5q + (u + 1) * 32 + 4);
            }
            const unsigned m0 = ((k2 ? c0.y : c0.x) >> (quad * 8)) & 0xffu;
            const unsigned m1 = ((k2 ? c1.y : c1.x) >> (quad * 8)) & 0xffu;
            const unsigned m2 = ((k2 ? c2.y : c2.x) >> (quad * 8)) & 0xffu;
            const unsigned m3 = ((k2 ? c3.y : c3.x) >> (quad * 8)) & 0xffu;
            const float ev[8]  = {cEa.x, cEa.y, cEa.z, cEa.w, cEb.x, cEb.y, cEb.z, cEb.w};
            const float fv[8]  = {cFa.x, cFa.y, cFa.z, cFa.w, cFb.x, cFb.y, cFb.z, cFb.w};

            half8 p0, p1, p2, p3;
            #pragma unroll
            for (int j = 0; j < 8; ++j) {
                const float e = ev[j], f = fv[j];
                float v;
                v = (e >= Tc[0]) ? e * Kc[0] : f * Mc[0];
                v = (m0 & (1u << j)) ? v : 0.f;
                dsum[0] += v; p0[j] = (_Float16)v;
                v = (e >= Tc[1]) ? e * Kc[1] : f * Mc[1];
                v = (m1 & (1u << j)) ? v : 0.f;
                dsum[1] += v; p1[j] = (_Float16)v;
                v = (e >= Tc[2]) ? e * Kc[2] : f * Mc[2];
                v = (m2 & (1u << j)) ? v : 0.f;
                dsum[2] += v; p2[j] = (_Float16)v;
                v = (e >= Tc[3]) ? e * Kc[3] : f * Mc[3];
                v = (m3 & (1u << j)) ? v : 0.f;
                dsum[3] += v; p3[j] = (_Float16)v;
            }

            const int lbase = (k2 * 4 + quad) * 1024 + l15 * 8;
            #pragma unroll
            for (int t = 0; t < 8; ++t) {
                half8 bf = *reinterpret_cast<const half8*>(
                    &sB[cur][lbase + t * 128]);
                acc[0][t] = __builtin_amdgcn_mfma_f32_16x16x32_f16(p0, bf, acc[0][t], 0, 0, 0);
                acc[1][t] = __builtin_amdgcn_mfma_f32_16x16x32_f16(p1, bf, acc[1][t], 0, 0, 0);
                acc[2][t] = __builtin_amdgcn_mfma_f32_16x16x32_f16(p2, bf, acc[2][t], 0, 0, 0);
                acc[3][t] = __builtin_amdgcn_mfma_f32_16x16x32_f16(p3, bf, acc[3][t], 0, 0, 0);
            }
        }
        __syncthreads();
    }
    #undef STAGE

    // Row denominators (full row sums after quad reduction); fh==0 writes.
    #pragma unroll
    for (int s = 0; s < 4; ++s) {
        dsum[s] += __shfl_xor(dsum[s], 16);
        dsum[s] += __shfl_xor(dsum[s], 32);
    }
    if (fh == 0 && lane < 16) {
        float* Lq = L + q * GAT_N;
        #pragma unroll
        for (int s = 0; s < 4; ++s) Lq[r0 + s * 16 + l15] = dsum[s];
    }

    // Permuted fp16 partial store: per (q,wid): 16384 halves, fh-half 8192.
    const int wid = rb * 4 + wv;                       // 0..127 (64 rows each)
    _Float16* Pq = Ph + ((size_t)(q * 128 + wid) * 16384) + fh * 8192;
    #pragma unroll
    for (int s = 0; s < 4; ++s)
        #pragma unroll
        for (int t = 0; t < 8; ++t) {
            half4 hv;
            #pragma unroll
            for (int r = 0; r < 4; ++r) hv[r] = (_Float16)acc[s][t][r];
            *reinterpret_cast<half4*>(Pq + (size_t)(((s * 8 + t) * 64 + lane) * 4)) = hv;
        }
}

// ---------------------------------------------------------------------------
// K4: un-permute + combine 8 fp16 partials, normalize, ELU, write out.
// 2048 blocks x 256 thr; 16 blocks per wid (wid = 64 rows).
// ---------------------------------------------------------------------------
__global__ __launch_bounds__(256) void gat_k4_final(
    const _Float16* __restrict__ Ph, const float* __restrict__ L,
    float* __restrict__ out)
{
    const int tid = threadIdx.x;
    const int wid = blockIdx.x >> 4;                   // 0..127
    __shared__ float s_rl[64];
    if (tid < 64) {
        const int row = wid * 64 + tid;
        float s = 0.f;
        #pragma unroll
        for (int q = 0; q < 8; ++q) s += L[q * GAT_N + row];
        s_rl[tid] = 1.0f / fmaxf(s, 1e-30f);
    }
    __syncthreads();

    const int idx = blockIdx.x * 256 + tid;            // half4 position
    const int rem = idx & 4095;                        // within wid (4096 h4)
    const int fh = rem >> 11;
    const int r2 = rem & 2047;                         // (s*8+t)*64 + lane
    const int st = r2 >> 6;
    const int s = st >> 3, t = st & 7;
    const int lane = r2 & 63;
    const int l15 = lane & 15, quad = lane >> 4;
    const int lrow0 = s * 16 + quad * 4;               // local rows lrow0..+3
    const int col = fh * 128 + t * 16 + l15;

    float accv[4] = {0.f, 0.f, 0.f, 0.f};
    #pragma unroll
    for (int q = 0; q < 8; ++q) {
        half4 v = *reinterpret_cast<const half4*>(
            Ph + ((size_t)(q * 128 + wid) * 16384) + fh * 8192 + (size_t)r2 * 4);
        #pragma unroll
        for (int r = 0; r < 4; ++r) accv[r] += (float)v[r];
    }
    #pragma unroll
    for (int r = 0; r < 4; ++r) {
        const float v = accv[r] * s_rl[lrow0 + r];
        const float o = v > 0.f ? v : expm1f(v);
        out[(size_t)(wid * 64 + lrow0 + r) * GAT_F + col] = o;
    }
}

// ---------------------------------------------------------------------------
extern "C" void kernel_launch(void* const* d_in, const int* in_sizes, int n_in,
                              void* d_out, int out_size, void* d_ws, size_t ws_size,
                              hipStream_t stream)
{
    const float* h   = (const float*)d_in[0];
    const int*   adj = (const int*)d_in[1];
    // d_in[2] = cv_values: constant per softmax row -> cancels exactly; unused.
    const float* W   = (const float*)d_in[3];
    const float* a   = (const float*)d_in[4];
    float* out = (float*)d_out;
    char* ws = (char*)d_ws;

    const size_t SLAB = (size_t)GAT_N * GAT_F * 2;     // 4 MiB (fp16 matrix)

    size_t off = 0;
    _Float16* whT = (_Float16*)(ws + off); off += SLAB;            // 4 MiB
    _Float16* Ph  = (_Float16*)(ws + off); off += 8 * SLAB;        // 32 MiB
    unsigned char* adjB = (unsigned char*)(ws + off); off += (size_t)GAT_N * GAT_N / 8; // 8 MiB
    _Float16* WT  = (_Float16*)(ws + off); off += (size_t)GAT_F * GAT_F * 2;            // 128 KiB
    float* f1L = (float*)(ws + off); off += GAT_N * 4;
    float* f2L = (float*)(ws + off); off += GAT_N * 4;
    float* Etb = (float*)(ws + off); off += GAT_N * 4;
    float* E5tb = (float*)(ws + off); off += GAT_N * 4;
    float* L   = (float*)(ws + off); off += 8 * GAT_N * 4;
    unsigned* f2mxEnc = (unsigned*)(ws + off); off += 256;

    gat_k0_pack<<<2048, 256, 0, stream>>>(adj, adjB);
    gat_k0b_convert<<<256, 256, 0, stream>>>(W, WT, f2mxEnc);
    gat_k1_gemm<<<512, 256, 0, stream>>>(h, WT, a, whT, f1L, f2L, f2mxEnc);
    gat_k2e_tables<<<32, 256, 0, stream>>>(f2L, f2mxEnc, Etb, E5tb);
    gat_k3_attn<<<512, 256, 0, stream>>>((const unsigned*)adjB, f1L, f2mxEnc,
                                         Etb, E5tb, whT, Ph, L);
    gat_k4_final<<<2048, 256, 0, stream>>>(Ph, L, out);
}

// Round 9
// 477.971 us; speedup vs baseline: 1.0015x; 1.0015x over previous
//
#include <hip/hip_runtime.h>
#include <cstdint>
#include <cstddef>

typedef _Float16 half8 __attribute__((ext_vector_type(8)));
typedef _Float16 half4 __attribute__((ext_vector_type(4)));
typedef float f32x4 __attribute__((ext_vector_type(4)));

#define GAT_N 8192
#define GAT_F 256
#define GAT_NW 256   // adj bitmask words per row (8192/32)
#define GAT_NQ 6     // key slices (uneven: 2x1408 + 4x1344, all %64==0)
#define GAT_ALPHA 0.2f
#define GAT_LOG2E 1.4426950408889634f

// Monotone float->uint encoding for atomicMax over floats of any sign.
__device__ inline unsigned enc_f32(float x) {
    unsigned b = __float_as_uint(x);
    return (b & 0x80000000u) ? ~b : (b | 0x80000000u);
}
__device__ inline float dec_f32(unsigned u) {
    unsigned b = (u & 0x80000000u) ? (u ^ 0x80000000u) : ~u;
    return __uint_as_float(b);
}

// ---------------------------------------------------------------------------
// K0a: bit-pack adj (int32 0/1, 268 MB) -> adjB (1 bit/edge, 8 MB).
// ---------------------------------------------------------------------------
__global__ __launch_bounds__(256) void gat_k0_pack(
    const int* __restrict__ adj, unsigned char* __restrict__ adjB)
{
    const int wv = threadIdx.x >> 6;
    const int lane = threadIdx.x & 63;
    const int row = blockIdx.x * 4 + wv;
    const int* src = adj + (size_t)row * GAT_N;
    unsigned char* dst = adjB + (size_t)row * (GAT_N / 8);
    #pragma unroll 4
    for (int k = 0; k < 16; ++k) {
        const int4 v0 = *reinterpret_cast<const int4*>(src + k * 512 + lane * 8);
        const int4 v1 = *reinterpret_cast<const int4*>(src + k * 512 + lane * 8 + 4);
        unsigned m = (unsigned)(v0.x > 0)        | ((unsigned)(v0.y > 0) << 1)
                   | ((unsigned)(v0.z > 0) << 2) | ((unsigned)(v0.w > 0) << 3)
                   | ((unsigned)(v1.x > 0) << 4) | ((unsigned)(v1.y > 0) << 5)
                   | ((unsigned)(v1.z > 0) << 6) | ((unsigned)(v1.w > 0) << 7);
        dst[k * 64 + lane] = (unsigned char)m;
    }
}

// ---------------------------------------------------------------------------
// K0b: W -> fp16 transposed WT[n][k]; init encoded f2max.
// ---------------------------------------------------------------------------
__global__ __launch_bounds__(256) void gat_k0b_convert(
    const float* __restrict__ W, _Float16* __restrict__ WT,
    unsigned* __restrict__ f2mxEnc)
{
    const int g = blockIdx.x * 256 + threadIdx.x;
    if (g == 0) *f2mxEnc = 0u;                          // enc(-FLT_MAX)
    const int k = g >> 8, n = g & 255;
    WT[n * GAT_F + k] = (_Float16)W[g];
}

// ---------------------------------------------------------------------------
// K1: Wh = h @ W via fp16 MFMA. grid 512 x 256 thr: block = 16 rows,
// wave wv = col-quarter (64 cols, 4 tiles). Cross-wave f1/f2 via LDS.
// ---------------------------------------------------------------------------
__global__ __launch_bounds__(256, 2) void gat_k1_gemm(
    const float* __restrict__ h, const _Float16* __restrict__ WT,
    const float* __restrict__ a, _Float16* __restrict__ whT,
    float* __restrict__ f1L, float* __restrict__ f2L,
    unsigned* __restrict__ f2mxEnc)
{
    __shared__ float sP1[4][16], sP2[4][16];
    const int wv = threadIdx.x >> 6;
    const int lane = threadIdx.x & 63;
    const int l15 = lane & 15;
    const int quad = lane >> 4;
    const int r0 = blockIdx.x * 16;

    f32x4 acc[4];
    #pragma unroll
    for (int t = 0; t < 4; ++t) { f32x4 z = {0.f,0.f,0.f,0.f}; acc[t] = z; }

    #pragma unroll
    for (int k0 = 0; k0 < GAT_F; k0 += 32) {
        const float* ap = h + (size_t)(r0 + l15) * GAT_F + k0 + quad * 8;
        const float4 a0 = *reinterpret_cast<const float4*>(ap);
        const float4 a1 = *reinterpret_cast<const float4*>(ap + 4);
        half8 af;
        af[0] = (_Float16)a0.x; af[1] = (_Float16)a0.y;
        af[2] = (_Float16)a0.z; af[3] = (_Float16)a0.w;
        af[4] = (_Float16)a1.x; af[5] = (_Float16)a1.y;
        af[6] = (_Float16)a1.z; af[7] = (_Float16)a1.w;
        #pragma unroll
        for (int t = 0; t < 4; ++t) {
            half8 bf = *reinterpret_cast<const half8*>(
                WT + (size_t)(wv * 64 + t * 16 + l15) * GAT_F + k0 + quad * 8);
            acc[t] = __builtin_amdgcn_mfma_f32_16x16x32_f16(af, bf, acc[t], 0, 0, 0);
        }
    }

    float p1[4] = {0.f,0.f,0.f,0.f}, p2[4] = {0.f,0.f,0.f,0.f};
    #pragma unroll
    for (int t = 0; t < 4; ++t) {
        float a1c = a[wv * 64 + t * 16 + l15];
        float a2c = a[GAT_F + wv * 64 + t * 16 + l15];
        #pragma unroll
        for (int r = 0; r < 4; ++r) {
            p1[r] = fmaf(acc[t][r], a1c, p1[r]);
            p2[r] = fmaf(acc[t][r], a2c, p2[r]);
        }
    }
    #pragma unroll
    for (int off = 1; off < 16; off <<= 1) {
        #pragma unroll
        for (int r = 0; r < 4; ++r) {
            p1[r] += __shfl_xor(p1[r], off);
            p2[r] += __shfl_xor(p2[r], off);
        }
    }
    if (l15 == 0) {
        #pragma unroll
        for (int r = 0; r < 4; ++r) {
            sP1[wv][quad * 4 + r] = p1[r];
            sP2[wv][quad * 4 + r] = p2[r];
        }
    }
    __syncthreads();
    if (threadIdx.x < 16) {
        const int row = threadIdx.x;
        const float s1 = (sP1[0][row] + sP1[1][row] + sP1[2][row] + sP1[3][row]) * GAT_LOG2E;
        const float s2 = (sP2[0][row] + sP2[1][row] + sP2[2][row] + sP2[3][row]) * GAT_LOG2E;
        f1L[r0 + row] = s1;
        f2L[r0 + row] = s2;
        float mx = s2;
        #pragma unroll
        for (int off = 1; off < 16; off <<= 1) mx = fmaxf(mx, __shfl_xor(mx, off));
        if (row == 0) atomicMax(f2mxEnc, enc_f32(mx));
    }

    #pragma unroll
    for (int t = 0; t < 4; ++t) {
        half4 hv;
        #pragma unroll
        for (int r = 0; r < 4; ++r) hv[r] = (_Float16)acc[t][r];
        *reinterpret_cast<half4*>(
            whT + (size_t)(wv * 64 + t * 16 + l15) * GAT_N + r0 + quad * 4) = hv;
    }
}

// ---------------------------------------------------------------------------
// K3: fused masked softmax-numerator x V (R7 structure, tail-free grid).
// grid = 64 rb x 6 q x 2 fh = 768 blocks = EXACTLY 3 blocks/CU at (256,3),
// 12 waves/CU (the empirically best coverage: R6 8w=483, R7 12w=466, R8
// 8w=479 -> waves/CU dominates; R7's only defect was its 256-block tail).
// Uneven key slices {1408,1408,1344,1344,1344,1344} (all %64==0) make the
// 6-way split exact. Block: 128 rows x 128 feats (fh half); wave: 32 rows
// (2 strips); acc = 2x8x4 = 64 AGPR (AGPR+VGPR share the 512/3~170 budget ->
// ~100 VGPR working set fits, no spill). BK=64 double-buffered LDS
// (2 x 16 KB), key-oct-major conflict-free layout. uint2 adj/step prefetch.
// ---------------------------------------------------------------------------
__global__ __launch_bounds__(256, 3) void gat_k3_attn(
    const unsigned* __restrict__ adjW, const float* __restrict__ f1L,
    const float* __restrict__ f2L, const unsigned* __restrict__ f2mxEnc,
    const _Float16* __restrict__ whT,
    _Float16* __restrict__ Ph,     // 6 slabs x 8192x256 fp16, permuted
    float* __restrict__ L)         // [6][8192]
{
    __shared__ __align__(16) _Float16 sB[2][8192];   // 2 x 16 KB (64-key tile)

    const int bx = blockIdx.x;
    const int q  = bx % 6;           // key slice 0..5
    const int fh = (bx / 6) & 1;     // feature half
    const int rb = bx / 12;          // row group 0..63
    const int wv = threadIdx.x >> 6;
    const int lane = threadIdx.x & 63;
    const int l15 = lane & 15;
    const int quad = lane >> 4;

    const int OFFS[6]  = {0, 1408, 2816, 4160, 5504, 6848};
    const int NSTEP[6] = {22, 22, 21, 21, 21, 21};
    const int kq = OFFS[q];
    const int nsteps = NSTEP[q];      // 64-key steps in this slice

    const int r0 = rb * 128 + wv * 32;
    const int rA = r0 + l15;
    const int rB = rA + 16;

    const float fmxL = dec_f32(*f2mxEnc);
    const float f1A = f1L[rA];
    const float f1B = f1L[rB];
    const float sA = f1A + fmxL;
    const float sBv = f1B + fmxL;
    const float CA = fmaxf(sA, GAT_ALPHA * sA);
    const float CB = fmaxf(sBv, GAT_ALPHA * sBv);

    f32x4 acc[2][8];
    #pragma unroll
    for (int s = 0; s < 2; ++s)
        #pragma unroll
        for (int t = 0; t < 8; ++t) {
            f32x4 z = {0.f,0.f,0.f,0.f};
            acc[s][t] = z;
        }
    float d0 = 0.f, d1 = 0.f;

    const uint2* awA = reinterpret_cast<const uint2*>(adjW + (size_t)rA * GAT_NW + (kq >> 5));
    const uint2* awB = reinterpret_cast<const uint2*>(adjW + (size_t)rB * GAT_NW + (kq >> 5));
    const float* f2q = f2L + kq + quad * 8;

    // Staging: 128 feats x 64 keys (16 KB), 4 instr/wave, key-oct-major
    // (chunk = koct*128 + feat -> 2 lanes/bank-group per phase = conflict-free).
    const _Float16* gst = whT + (size_t)(fh * 128 + lane) * GAT_N + kq + wv * 8;
    #define STAGE(buf, step)                                                   \
        {                                                                      \
            _Pragma("unroll")                                                  \
            for (int i = 0; i < 4; ++i) {                                      \
                const _Float16* gp = gst + (size_t)((i & 1) * 64) * GAT_N      \
                                     + (i >> 1) * 32 + (step) * 64;            \
                _Float16* lp = &sB[buf][((wv + (i >> 1) * 4) * 128             \
                                         + (i & 1) * 64) * 8];                 \
                __builtin_amdgcn_global_load_lds(                              \
                    (const __attribute__((address_space(1))) void*)gp,         \
                    (__attribute__((address_space(3))) void*)lp, 16, 0, 0);    \
            }                                                                  \
        }

    uint2 nA = awA[0];
    uint2 nB = awB[0];
    float4 nfa = *reinterpret_cast<const float4*>(f2q);
    float4 nfb = *reinterpret_cast<const float4*>(f2q + 4);
    STAGE(0, 0)
    __syncthreads();   // buf0 staged (barrier drains vmcnt)

    for (int step = 0; step < nsteps; ++step) {   // 64 keys per step
        const int cur = step & 1;
        const uint2 cA = nA, cB = nB;
        if (step + 1 < nsteps) {
            nA = awA[step + 1];
            nB = awB[step + 1];
            STAGE(1 - cur, step + 1)
        }

        #pragma unroll
        for (int k2 = 0; k2 < 2; ++k2) {    // sub = 32 keys (one MFMA K)
            const int u = step * 2 + k2;
            const float4 cfa = nfa, cfb = nfb;
            if (u + 1 < 2 * nsteps) {
                nfa = *reinterpret_cast<const float4*>(f2q + (u + 1) * 32);
                nfb = *reinterpret_cast<const float4*>(f2q + (u + 1) * 32 + 4);
            }
            const unsigned wA = k2 ? cA.y : cA.x;
            const unsigned wB = k2 ? cB.y : cB.x;
            const unsigned mA = (wA >> (quad * 8)) & 0xffu;
            const unsigned mB = (wB >> (quad * 8)) & 0xffu;
            const float f2v[8] = {cfa.x, cfa.y, cfa.z, cfa.w,
                                  cfb.x, cfb.y, cfb.z, cfb.w};

            half8 pA, pB;
            #pragma unroll
            for (int j = 0; j < 8; ++j) {
                const float f2j = f2v[j];
                float xa = f1A + f2j;
                float la = fmaxf(xa, GAT_ALPHA * xa);
                float pa = __builtin_amdgcn_exp2f(la - CA);
                pa = (mA & (1u << j)) ? pa : 0.f;
                d0 += pa;
                pA[j] = (_Float16)pa;
                float xb = f1B + f2j;
                float lb = fmaxf(xb, GAT_ALPHA * xb);
                float pb = __builtin_amdgcn_exp2f(lb - CB);
                pb = (mB & (1u << j)) ? pb : 0.f;
                d1 += pb;
                pB[j] = (_Float16)pb;
            }

            // chunk = (k2*4+quad)*128 + t*16 + l15 ; halves = chunk*8
            const int lbase = (k2 * 4 + quad) * 1024 + l15 * 8;
            #pragma unroll
            for (int t = 0; t < 8; ++t) {
                half8 bf = *reinterpret_cast<const half8*>(
                    &sB[cur][lbase + t * 128]);
                acc[0][t] = __builtin_amdgcn_mfma_f32_16x16x32_f16(pA, bf, acc[0][t], 0, 0, 0);
                acc[1][t] = __builtin_amdgcn_mfma_f32_16x16x32_f16(pB, bf, acc[1][t], 0, 0, 0);
            }
        }
        __syncthreads();   // drains stage(step+1) + this step's ds_reads
    }
    #undef STAGE

    // Row denominators (identical in both fh halves; fh==0 writes).
    d0 += __shfl_xor(d0, 16); d0 += __shfl_xor(d0, 32);
    d1 += __shfl_xor(d1, 16); d1 += __shfl_xor(d1, 32);
    if (fh == 0 && lane < 16) {
        float* Lq = L + q * GAT_N;
        Lq[rA] = d0; Lq[rB] = d1;
    }

    // Coalesced permuted fp16 partial store; fh selects tile range.
    const int wid = rb * 4 + wv;                       // 0..255
    _Float16* Pq = Ph + ((size_t)q * 256 + wid) * 8192;
    #pragma unroll
    for (int s = 0; s < 2; ++s)
        #pragma unroll
        for (int t = 0; t < 8; ++t) {
            const int tt = fh * 8 + t;
            half4 hv;
            #pragma unroll
            for (int r = 0; r < 4; ++r) hv[r] = (_Float16)acc[s][t][r];
            *reinterpret_cast<half4*>(Pq + (size_t)(((s * 16 + tt) * 64 + lane) * 4)) = hv;
        }
}

// ---------------------------------------------------------------------------
// K4: un-permute + combine 6 fp16 partials, normalize, ELU, write out.
// ---------------------------------------------------------------------------
__global__ __launch_bounds__(256) void gat_k4_final(
    const _Float16* __restrict__ Ph, const float* __restrict__ L,
    float* __restrict__ out)
{
    const int tid = threadIdx.x;
    const int wid = blockIdx.x >> 3;                   // wave-chunk 0..255
    __shared__ float s_rl[32];
    if (tid < 32) {
        const int row = wid * 32 + tid;
        float s = 0.f;
        #pragma unroll
        for (int q = 0; q < GAT_NQ; ++q) s += L[q * GAT_N + row];
        s_rl[tid] = 1.0f / fmaxf(s, 1e-30f);
    }
    __syncthreads();

    const int idx = blockIdx.x * 256 + tid;            // half4 position
    const int rem = idx & 2047;                        // within wave-chunk
    const int lane = rem & 63;
    const int st = rem >> 6;
    const int s = st >> 4, t = st & 15;
    const int l15 = lane & 15, quad = lane >> 4;
    const int lrow0 = s * 16 + quad * 4;               // local rows lrow0..+3
    const int col = t * 16 + l15;

    float accv[4] = {0.f, 0.f, 0.f, 0.f};
    #pragma unroll
    for (int q = 0; q < GAT_NQ; ++q) {
        half4 v = *reinterpret_cast<const half4*>(
            Ph + ((size_t)q * 256 + wid) * 8192 + (size_t)rem * 4);
        #pragma unroll
        for (int r = 0; r < 4; ++r) accv[r] += (float)v[r];
    }
    #pragma unroll
    for (int r = 0; r < 4; ++r) {
        const float v = accv[r] * s_rl[lrow0 + r];
        const float o = v > 0.f ? v : expm1f(v);
        out[(size_t)(wid * 32 + lrow0 + r) * GAT_F + col] = o;
    }
}

// ---------------------------------------------------------------------------
extern "C" void kernel_launch(void* const* d_in, const int* in_sizes, int n_in,
                              void* d_out, int out_size, void* d_ws, size_t ws_size,
                              hipStream_t stream)
{
    const float* h   = (const float*)d_in[0];
    const int*   adj = (const int*)d_in[1];
    // d_in[2] = cv_values: constant per softmax row -> cancels exactly; unused.
    const float* W   = (const float*)d_in[3];
    const float* a   = (const float*)d_in[4];
    float* out = (float*)d_out;
    char* ws = (char*)d_ws;

    const size_t SLAB = (size_t)GAT_N * GAT_F * 2;     // 4 MiB (fp16 matrix)

    size_t off = 0;
    _Float16* whT = (_Float16*)(ws + off); off += SLAB;            // 4 MiB
    _Float16* Ph  = (_Float16*)(ws + off); off += GAT_NQ * SLAB;   // 24 MiB
    unsigned char* adjB = (unsigned char*)(ws + off); off += (size_t)GAT_N * GAT_N / 8; // 8 MiB
    _Float16* WT  = (_Float16*)(ws + off); off += (size_t)GAT_F * GAT_F * 2;            // 128 KiB
    float* f1L = (float*)(ws + off); off += GAT_N * 4;
    float* f2L = (float*)(ws + off); off += GAT_N * 4;
    float* L   = (float*)(ws + off); off += GAT_NQ * GAT_N * 4;
    unsigned* f2mxEnc = (unsigned*)(ws + off); off += 256;

    gat_k0_pack<<<2048, 256, 0, stream>>>(adj, adjB);
    gat_k0b_convert<<<256, 256, 0, stream>>>(W, WT, f2mxEnc);
    gat_k1_gemm<<<512, 256, 0, stream>>>(h, WT, a, whT, f1L, f2L, f2mxEnc);
    gat_k3_attn<<<768, 256, 0, stream>>>((const unsigned*)adjB, f1L, f2L, f2mxEnc, whT, Ph, L);
    gat_k4_final<<<2048, 256, 0, stream>>>(Ph, L, out);
}

// Round 11
// 455.236 us; speedup vs baseline: 1.0515x; 1.0499x over previous
//
#include <hip/hip_runtime.h>
#include <cstdint>
#include <cstddef>

typedef _Float16 half8 __attribute__((ext_vector_type(8)));
typedef _Float16 half4 __attribute__((ext_vector_type(4)));
typedef float f32x4 __attribute__((ext_vector_type(4)));

#define GAT_N 8192
#define GAT_F 256
#define GAT_NW 256   // adj bitmask words per row (8192/32)
#define GAT_NQ 8     // key slices of 1024
#define GAT_ALPHA 0.2f
#define GAT_LOG2E 1.4426950408889634f

// Monotone float->uint encoding for atomicMax over floats of any sign.
__device__ inline unsigned enc_f32(float x) {
    unsigned b = __float_as_uint(x);
    return (b & 0x80000000u) ? ~b : (b | 0x80000000u);
}
__device__ inline float dec_f32(unsigned u) {
    unsigned b = (u & 0x80000000u) ? (u ^ 0x80000000u) : ~u;
    return __uint_as_float(b);
}

// whT2 layout: 128 tiles (64 keys each) x [oct(8)][feat(256)][key&7(8)] fp16.
// addr(halves) = (key>>6)*16384 + ((key&63)>>3)*2048 + feat*8 + (key&7).
// This is EXACTLY the K3 LDS chunk order, so staging is a linear copy with
// unit-stride lanes. R10 bug: STAGE's global pointer was wave-uniform (all
// lanes read the same 16B); global_load_lds takes a PER-LANE global address
// with implicit lane*16 LDS dest -> must add lane*8 halves to the source.

// ---------------------------------------------------------------------------
// K0a: bit-pack adj (int32 0/1, 268 MB) -> adjB (1 bit/edge, 8 MB).
// ---------------------------------------------------------------------------
__global__ __launch_bounds__(256) void gat_k0_pack(
    const int* __restrict__ adj, unsigned char* __restrict__ adjB)
{
    const int wv = threadIdx.x >> 6;
    const int lane = threadIdx.x & 63;
    const int row = blockIdx.x * 4 + wv;
    const int* src = adj + (size_t)row * GAT_N;
    unsigned char* dst = adjB + (size_t)row * (GAT_N / 8);
    #pragma unroll 4
    for (int k = 0; k < 16; ++k) {
        const int4 v0 = *reinterpret_cast<const int4*>(src + k * 512 + lane * 8);
        const int4 v1 = *reinterpret_cast<const int4*>(src + k * 512 + lane * 8 + 4);
        unsigned m = (unsigned)(v0.x > 0)        | ((unsigned)(v0.y > 0) << 1)
                   | ((unsigned)(v0.z > 0) << 2) | ((unsigned)(v0.w > 0) << 3)
                   | ((unsigned)(v1.x > 0) << 4) | ((unsigned)(v1.y > 0) << 5)
                   | ((unsigned)(v1.z > 0) << 6) | ((unsigned)(v1.w > 0) << 7);
        dst[k * 64 + lane] = (unsigned char)m;
    }
}

// ---------------------------------------------------------------------------
// K0b: W -> fp16 transposed WT[n][k]; init encoded f2max.
// ---------------------------------------------------------------------------
__global__ __launch_bounds__(256) void gat_k0b_convert(
    const float* __restrict__ W, _Float16* __restrict__ WT,
    unsigned* __restrict__ f2mxEnc)
{
    const int g = blockIdx.x * 256 + threadIdx.x;
    if (g == 0) *f2mxEnc = 0u;                          // enc(-FLT_MAX)
    const int k = g >> 8, n = g & 255;
    WT[n * GAT_F + k] = (_Float16)W[g];
}

// ---------------------------------------------------------------------------
// K1: Wh = h @ W via fp16 MFMA. grid 512 x 256 thr: block = 16 rows (=16
// keys), wave wv = col-quarter (64 cols, 4 tiles). Cross-wave f1/f2 via LDS.
// Epilogue writes whT2 in TILED layout (key of K3 = row of Wh).
// ---------------------------------------------------------------------------
__global__ __launch_bounds__(256, 2) void gat_k1_gemm(
    const float* __restrict__ h, const _Float16* __restrict__ WT,
    const float* __restrict__ a, _Float16* __restrict__ whT2,
    float* __restrict__ f1L, float* __restrict__ f2L,
    unsigned* __restrict__ f2mxEnc)
{
    __shared__ float sP1[4][16], sP2[4][16];
    const int wv = threadIdx.x >> 6;
    const int lane = threadIdx.x & 63;
    const int l15 = lane & 15;
    const int quad = lane >> 4;
    const int r0 = blockIdx.x * 16;

    f32x4 acc[4];
    #pragma unroll
    for (int t = 0; t < 4; ++t) { f32x4 z = {0.f,0.f,0.f,0.f}; acc[t] = z; }

    #pragma unroll
    for (int k0 = 0; k0 < GAT_F; k0 += 32) {
        const float* ap = h + (size_t)(r0 + l15) * GAT_F + k0 + quad * 8;
        const float4 a0 = *reinterpret_cast<const float4*>(ap);
        const float4 a1 = *reinterpret_cast<const float4*>(ap + 4);
        half8 af;
        af[0] = (_Float16)a0.x; af[1] = (_Float16)a0.y;
        af[2] = (_Float16)a0.z; af[3] = (_Float16)a0.w;
        af[4] = (_Float16)a1.x; af[5] = (_Float16)a1.y;
        af[6] = (_Float16)a1.z; af[7] = (_Float16)a1.w;
        #pragma unroll
        for (int t = 0; t < 4; ++t) {
            half8 bf = *reinterpret_cast<const half8*>(
                WT + (size_t)(wv * 64 + t * 16 + l15) * GAT_F + k0 + quad * 8);
            acc[t] = __builtin_amdgcn_mfma_f32_16x16x32_f16(af, bf, acc[t], 0, 0, 0);
        }
    }

    float p1[4] = {0.f,0.f,0.f,0.f}, p2[4] = {0.f,0.f,0.f,0.f};
    #pragma unroll
    for (int t = 0; t < 4; ++t) {
        float a1c = a[wv * 64 + t * 16 + l15];
        float a2c = a[GAT_F + wv * 64 + t * 16 + l15];
        #pragma unroll
        for (int r = 0; r < 4; ++r) {
            p1[r] = fmaf(acc[t][r], a1c, p1[r]);
            p2[r] = fmaf(acc[t][r], a2c, p2[r]);
        }
    }
    #pragma unroll
    for (int off = 1; off < 16; off <<= 1) {
        #pragma unroll
        for (int r = 0; r < 4; ++r) {
            p1[r] += __shfl_xor(p1[r], off);
            p2[r] += __shfl_xor(p2[r], off);
        }
    }
    if (l15 == 0) {
        #pragma unroll
        for (int r = 0; r < 4; ++r) {
            sP1[wv][quad * 4 + r] = p1[r];
            sP2[wv][quad * 4 + r] = p2[r];
        }
    }
    __syncthreads();
    if (threadIdx.x < 16) {
        const int row = threadIdx.x;
        const float s1 = (sP1[0][row] + sP1[1][row] + sP1[2][row] + sP1[3][row]) * GAT_LOG2E;
        const float s2 = (sP2[0][row] + sP2[1][row] + sP2[2][row] + sP2[3][row]) * GAT_LOG2E;
        f1L[r0 + row] = s1;
        f2L[r0 + row] = s2;
        float mx = s2;
        #pragma unroll
        for (int off = 1; off < 16; off <<= 1) mx = fmaxf(mx, __shfl_xor(mx, off));
        if (row == 0) atomicMax(f2mxEnc, enc_f32(mx));
    }

    // Tiled whT2 store. Keys r0+quad*4+r, feat c:
    // tile = r0>>6, oct = ((r0&63)>>3)+(quad>>1), key&7 = (quad&1)*4+r.
    const size_t tbase = (size_t)(r0 >> 6) * 16384
                       + (((r0 & 63) >> 3) + (quad >> 1)) * 2048
                       + (quad & 1) * 4;
    #pragma unroll
    for (int t = 0; t < 4; ++t) {
        const int c = wv * 64 + t * 16 + l15;
        half4 hv;
        #pragma unroll
        for (int r = 0; r < 4; ++r) hv[r] = (_Float16)acc[t][r];
        *reinterpret_cast<half4*>(whT2 + tbase + c * 8) = hv;
    }
}

// ---------------------------------------------------------------------------
// K3: fused masked softmax-numerator x V (R7 grid + tiled-whT2 staging).
// grid = 64 rb x 8 q x 2 fh = 1024 blocks at (256,3) -> 12 waves/CU.
// Block: 128 rows x 128 feats (fh half) x 1024-key slice, 16 steps of 64
// keys. STAGE is a LINEAR copy: each global_load_lds reads 1 KB of
// consecutive addresses (16B/lane unit stride -> 16 full lines, all L2
// channels) into the key-oct-major LDS layout (conflict-free ds_read_b128).
// acc = 2x8x4 = 64 AGPR; uint2 adj + f2 register prefetch as R9.
// ---------------------------------------------------------------------------
__global__ __launch_bounds__(256, 3) void gat_k3_attn(
    const unsigned* __restrict__ adjW, const float* __restrict__ f1L,
    const float* __restrict__ f2L, const unsigned* __restrict__ f2mxEnc,
    const _Float16* __restrict__ whT2,
    _Float16* __restrict__ Ph,     // 8 slabs x 8192x256 fp16, permuted
    float* __restrict__ L)         // [8][8192]
{
    __shared__ __align__(16) _Float16 sB[2][8192];   // 2 x 16 KB (64-key tile)

    const int bx = blockIdx.x;
    const int q  = bx & 7;           // key slice 0..7
    const int fh = (bx >> 3) & 1;    // feature half
    const int rb = bx >> 4;          // row group 0..63
    const int wv = threadIdx.x >> 6;
    const int lane = threadIdx.x & 63;
    const int l15 = lane & 15;
    const int quad = lane >> 4;

    const int kq = q * 1024;
    const int r0 = rb * 128 + wv * 32;
    const int rA = r0 + l15;
    const int rB = rA + 16;

    const float fmxL = dec_f32(*f2mxEnc);
    const float f1A = f1L[rA];
    const float f1B = f1L[rB];
    const float sA = f1A + fmxL;
    const float sBv = f1B + fmxL;
    const float CA = fmaxf(sA, GAT_ALPHA * sA);
    const float CB = fmaxf(sBv, GAT_ALPHA * sBv);

    f32x4 acc[2][8];
    #pragma unroll
    for (int s = 0; s < 2; ++s)
        #pragma unroll
        for (int t = 0; t < 8; ++t) {
            f32x4 z = {0.f,0.f,0.f,0.f};
            acc[s][t] = z;
        }
    float d0 = 0.f, d1 = 0.f;

    const uint2* awA = reinterpret_cast<const uint2*>(adjW + (size_t)rA * GAT_NW + q * 32);
    const uint2* awB = reinterpret_cast<const uint2*>(adjW + (size_t)rB * GAT_NW + q * 32);
    const float* f2q = f2L + kq + quad * 8;

    // STAGE(buf, step): copy fh-half of 64-key tile (16 KB) from whT2.
    // Wave wv covers kocts {2wv, 2wv+1}; instr i: koct = 2wv+(i>>1),
    // feat sub-half hh = i&1. Source = consecutive 1 KB; PER-LANE global
    // address = base + lane*8 halves (16 B/lane). LDS chunk = koct*128 +
    // hh*64 + lane (implicit lane*16 dest).
    const _Float16* tile0 = whT2 + (size_t)(q * 16) * 16384 + (size_t)fh * 1024
                          + (size_t)lane * 8;
    #define STAGE(buf, step)                                                   \
        {                                                                      \
            _Pragma("unroll")                                                  \
            for (int i = 0; i < 4; ++i) {                                      \
                const int koct = 2 * wv + (i >> 1);                            \
                const int hh = i & 1;                                          \
                const _Float16* gp = tile0 + (size_t)(step) * 16384            \
                                     + koct * 2048 + hh * 512;                 \
                _Float16* lp = &sB[buf][(koct * 128 + hh * 64) * 8];           \
                __builtin_amdgcn_global_load_lds(                              \
                    (const __attribute__((address_space(1))) void*)gp,         \
                    (__attribute__((address_space(3))) void*)lp, 16, 0, 0);    \
            }                                                                  \
        }

    uint2 nA = awA[0];
    uint2 nB = awB[0];
    float4 nfa = *reinterpret_cast<const float4*>(f2q);
    float4 nfb = *reinterpret_cast<const float4*>(f2q + 4);
    STAGE(0, 0)
    __syncthreads();   // buf0 staged (barrier drains vmcnt)

    for (int step = 0; step < 16; ++step) {   // 64 keys per step
        const int cur = step & 1;
        const uint2 cA = nA, cB = nB;
        if (step < 15) {
            nA = awA[step + 1];
            nB = awB[step + 1];
            STAGE(1 - cur, step + 1)
        }

        #pragma unroll
        for (int k2 = 0; k2 < 2; ++k2) {    // sub = 32 keys (one MFMA K)
            const int u = step * 2 + k2;
            const float4 cfa = nfa, cfb = nfb;
            if (u < 31) {
                nfa = *reinterpret_cast<const float4*>(f2q + (u + 1) * 32);
                nfb = *reinterpret_cast<const float4*>(f2q + (u + 1) * 32 + 4);
            }
            const unsigned wA = k2 ? cA.y : cA.x;
            const unsigned wB = k2 ? cB.y : cB.x;
            const unsigned mA = (wA >> (quad * 8)) & 0xffu;
            const unsigned mB = (wB >> (quad * 8)) & 0xffu;
            const float f2v[8] = {cfa.x, cfa.y, cfa.z, cfa.w,
                                  cfb.x, cfb.y, cfb.z, cfb.w};

            half8 pA, pB;
            #pragma unroll
            for (int j = 0; j < 8; ++j) {
                const float f2j = f2v[j];
                float xa = f1A + f2j;
                float la = fmaxf(xa, GAT_ALPHA * xa);
                float pa = __builtin_amdgcn_exp2f(la - CA);
                pa = (mA & (1u << j)) ? pa : 0.f;
                d0 += pa;
                pA[j] = (_Float16)pa;
                float xb = f1B + f2j;
                float lb = fmaxf(xb, GAT_ALPHA * xb);
                float pb = __builtin_amdgcn_exp2f(lb - CB);
                pb = (mB & (1u << j)) ? pb : 0.f;
                d1 += pb;
                pB[j] = (_Float16)pb;
            }

            // chunk = (k2*4+quad)*128 + t*16 + l15 ; halves = chunk*8
            const int lbase = (k2 * 4 + quad) * 1024 + l15 * 8;
            #pragma unroll
            for (int t = 0; t < 8; ++t) {
                half8 bf = *reinterpret_cast<const half8*>(
                    &sB[cur][lbase + t * 128]);
                acc[0][t] = __builtin_amdgcn_mfma_f32_16x16x32_f16(pA, bf, acc[0][t], 0, 0, 0);
                acc[1][t] = __builtin_amdgcn_mfma_f32_16x16x32_f16(pB, bf, acc[1][t], 0, 0, 0);
            }
        }
        __syncthreads();   // drains stage(step+1) + this step's ds_reads
    }
    #undef STAGE

    // Row denominators (identical in both fh halves; fh==0 writes).
    d0 += __shfl_xor(d0, 16); d0 += __shfl_xor(d0, 32);
    d1 += __shfl_xor(d1, 16); d1 += __shfl_xor(d1, 32);
    if (fh == 0 && lane < 16) {
        float* Lq = L + q * GAT_N;
        Lq[rA] = d0; Lq[rB] = d1;
    }

    // Coalesced permuted fp16 partial store; fh selects tile range.
    const int wid = rb * 4 + wv;                       // 0..255
    _Float16* Pq = Ph + ((size_t)q * 256 + wid) * 8192;
    #pragma unroll
    for (int s = 0; s < 2; ++s)
        #pragma unroll
        for (int t = 0; t < 8; ++t) {
            const int tt = fh * 8 + t;
            half4 hv;
            #pragma unroll
            for (int r = 0; r < 4; ++r) hv[r] = (_Float16)acc[s][t][r];
            *reinterpret_cast<half4*>(Pq + (size_t)(((s * 16 + tt) * 64 + lane) * 4)) = hv;
        }
}

// ---------------------------------------------------------------------------
// K4: un-permute + combine 8 fp16 partials, normalize, ELU, write out.
// ---------------------------------------------------------------------------
__global__ __launch_bounds__(256) void gat_k4_final(
    const _Float16* __restrict__ Ph, const float* __restrict__ L,
    float* __restrict__ out)
{
    const int tid = threadIdx.x;
    const int wid = blockIdx.x >> 3;                   // wave-chunk 0..255
    __shared__ float s_rl[32];
    if (tid < 32) {
        const int row = wid * 32 + tid;
        float s = 0.f;
        #pragma unroll
        for (int q = 0; q < GAT_NQ; ++q) s += L[q * GAT_N + row];
        s_rl[tid] = 1.0f / fmaxf(s, 1e-30f);
    }
    __syncthreads();

    const int idx = blockIdx.x * 256 + tid;            // half4 position
    const int rem = idx & 2047;                        // within wave-chunk
    const int lane = rem & 63;
    const int st = rem >> 6;
    const int s = st >> 4, t = st & 15;
    const int l15 = lane & 15, quad = lane >> 4;
    const int lrow0 = s * 16 + quad * 4;               // local rows lrow0..+3
    const int col = t * 16 + l15;

    float accv[4] = {0.f, 0.f, 0.f, 0.f};
    #pragma unroll
    for (int q = 0; q < GAT_NQ; ++q) {
        half4 v = *reinterpret_cast<const half4*>(
            Ph + ((size_t)q * 256 + wid) * 8192 + (size_t)rem * 4);
        #pragma unroll
        for (int r = 0; r < 4; ++r) accv[r] += (float)v[r];
    }
    #pragma unroll
    for (int r = 0; r < 4; ++r) {
        const float v = accv[r] * s_rl[lrow0 + r];
        const float o = v > 0.f ? v : expm1f(v);
        out[(size_t)(wid * 32 + lrow0 + r) * GAT_F + col] = o;
    }
}

// ---------------------------------------------------------------------------
extern "C" void kernel_launch(void* const* d_in, const int* in_sizes, int n_in,
                              void* d_out, int out_size, void* d_ws, size_t ws_size,
                              hipStream_t stream)
{
    const float* h   = (const float*)d_in[0];
    const int*   adj = (const int*)d_in[1];
    // d_in[2] = cv_values: constant per softmax row -> cancels exactly; unused.
    const float* W   = (const float*)d_in[3];
    const float* a   = (const float*)d_in[4];
    float* out = (float*)d_out;
    char* ws = (char*)d_ws;

    const size_t SLAB = (size_t)GAT_N * GAT_F * 2;     // 4 MiB (fp16 matrix)

    size_t off = 0;
    _Float16* whT2 = (_Float16*)(ws + off); off += SLAB;           // 4 MiB tiled
    _Float16* Ph  = (_Float16*)(ws + off); off += GAT_NQ * SLAB;   // 32 MiB
    unsigned char* adjB = (unsigned char*)(ws + off); off += (size_t)GAT_N * GAT_N / 8; // 8 MiB
    _Float16* WT  = (_Float16*)(ws + off); off += (size_t)GAT_F * GAT_F * 2;            // 128 KiB
    float* f1L = (float*)(ws + off); off += GAT_N * 4;
    float* f2L = (float*)(ws + off); off += GAT_N * 4;
    float* L   = (float*)(ws + off); off += GAT_NQ * GAT_N * 4;
    unsigned* f2mxEnc = (unsigned*)(ws + off); off += 256;

    gat_k0_pack<<<2048, 256, 0, stream>>>(adj, adjB);
    gat_k0b_convert<<<256, 256, 0, stream>>>(W, WT, f2mxEnc);
    gat_k1_gemm<<<512, 256, 0, stream>>>(h, WT, a, whT2, f1L, f2L, f2mxEnc);
    gat_k3_attn<<<1024, 256, 0, stream>>>((const unsigned*)adjB, f1L, f2L, f2mxEnc, whT2, Ph, L);
    gat_k4_final<<<2048, 256, 0, stream>>>(Ph, L, out);
}